// Round 2
// 75.216 us; speedup vs baseline: 1.0010x; 1.0010x over previous
//
#include <hip/hip_runtime.h>
#include <math.h>

// Problem constants (fixed by the reference file)
#define H_DIM 1024
#define N2    32        // N/2 modes
#define L_LEN 8192
#define TPB   256

// Factor l = i + 64*j, i<64, j<128; one block per h.
// out[h, i+64j] = sum_n Re( P[n,i] * Q[n,j] ),  P = 2*Ceff*z^i,  Q = (z^64)^j
// Real GEMM per block:  out2[j][i] = sum_{k<64} A[j,k]*B[k,i]
//   k = 2n+b:  A[j,2n]=Qr, A[j,2n+1]=-Qi ;  B[2n,i]=Pr, B[2n+1,i]=Pi
// Both A and B stored as round-to-nearest bf16.
#define KSA    72       // row length in bf16 elems (144 B)
#define KSB    72
#define A_ROWS 128      // j rows
#define B_ROWS 64       // i rows
#define A_OFF  0
#define B_OFF  (A_ROWS * KSA)    // element (ushort) offset

#define AB_BYTES ((A_ROWS * KSA + B_ROWS * KSB) * 2)   // 27648 B
#define PRM_W 11
#define SMEM_BYTES 32768          // f32 staging buffer size (overlays A/B + prm)

typedef __bf16 bf16x8 __attribute__((ext_vector_type(8)));
typedef float  f32x4  __attribute__((ext_vector_type(4)));

union B128 { float4 f4; bf16x8 b8; };

// pack bf16_rn(a), bf16_rn(b) into one u32 (low = a, high = b); +0x8000 bias
__device__ __forceinline__ unsigned pack_bf_rn(float a, float b) {
    unsigned ua = __float_as_uint(a) + 0x8000u;
    unsigned ub = __float_as_uint(b) + 0x8000u;
    return (ua >> 16) | (ub & 0xFFFF0000u);
}
__device__ __forceinline__ float2 cmulf(float2 a, float2 b) {
    return make_float2(fmaf(a.x, b.x, -(a.y * b.y)),
                       fmaf(a.x, b.y,  (a.y * b.x)));
}
// amp * cis(2*pi*rev), phase reduced in double (setup only, 32 lanes/block)
__device__ __forceinline__ float2 amp_cis(float amp, double rev) {
    double fr = rev - floor(rev);
    float r = (float)fr;
    float c = __builtin_amdgcn_cosf(r);
    float s = __builtin_amdgcn_sinf(r);
    return make_float2(amp * c, amp * s);
}

// Staging swizzle: XOR word bits 3-4 with bits 8-9 (= q of the writing lane).
// Involution, keeps 4-word (float4) groups intact, makes both the scalar
// staging writes and the float4 staging reads <=2-way bank conflicts (free).
__device__ __forceinline__ int swz(int l) {
    return l ^ (((l >> 8) & 3) << 3);
}

__global__ __launch_bounds__(TPB, 4) void s4d_mfma5_kernel(
    const float* __restrict__ C,           // (H, N2, 2)
    const float* __restrict__ log_dt,      // (H,)
    const float* __restrict__ log_A_real,  // (H, N2)
    const float* __restrict__ A_imag,      // (H, N2)
    float* __restrict__ out)               // (H, L)
{
    // One raw buffer, three overlapping uses separated by barriers:
    //   [0, 27648)      bf16 A/B tiles            (build -> fragment loads)
    //   [27648, 29056)  f32 prm per-mode params   (setup -> build)
    //   [0, 32768)      f32 transposed output stage (post-MFMA -> stores)
    __shared__ __align__(16) char smem_raw[SMEM_BYTES];
    unsigned short* smem  = (unsigned short*)smem_raw;
    float*          prm   = (float*)(smem_raw + AB_BYTES);
    float*          stage = (float*)smem_raw;

    const int h   = blockIdx.x;
    const int tid = threadIdx.x;

    // ---- per-mode setup (32 lanes, once per block) ----
    if (tid < N2) {
        const int n   = tid;
        const int idx = h * N2 + n;
        float dt  = expf(log_dt[h]);
        float are = -expf(log_A_real[idx]);   // Re(A)
        float aim = A_imag[idx];              // Im(A) >= 0
        float xr  = are * dt;                 // Re(dtA)
        float xi  = aim * dt;                 // Im(dtA)
        // Ceff = Cc * (exp(dtA)-1)/A   (fp32 libm)
        float ex = expf(xr);
        float s  = sinf(xi);
        float c  = cosf(xi);
        float er = ex * c - 1.0f;
        float ei = ex * s;
        float cr = C[idx * 2 + 0];
        float ci = C[idx * 2 + 1];
        float nr = cr * er - ci * ei;
        float ni = cr * ei + ci * er;
        float inv_den = 1.0f / (are * are + aim * aim);
        float Cr = (nr * are + ni * aim) * inv_den;
        float Ci = (ni * are - nr * aim) * inv_den;

        const double rev1 = (double)xi * 0.15915494309189535;  // revolutions per step
        float* p = &prm[n * PRM_W];
        float2 z  = amp_cis(__expf(xr),            rev1);
        float2 z8 = amp_cis(__expf(8.0f * xr),     8.0 * rev1);
        float2 w  = amp_cis(__expf(64.0f * xr),    64.0 * rev1);
        float2 zK = amp_cis(__expf(1024.0f * xr),  1024.0 * rev1);
        p[0] = 2.0f * Cr;  p[1] = 2.0f * Ci;
        p[2] = z.x;        p[3] = z.y;
        p[4] = z8.x;       p[5] = z8.y;
        p[6] = w.x;        p[7] = w.y;
        p[8] = zK.x;       p[9] = zK.y;
    }
    __syncthreads();

    const int n = tid & 31;        // mode owned by this thread (lane-consecutive LDS cols)
    const int g = tid >> 5;        // row group
    const float* p = &prm[n * PRM_W];

    // ---- build A (Q-side): rows jj = 16g..16g+15, value (Qr, -Qi) ----
    {
        float2 w  = make_float2(p[6], p[7]);          // z^64
        float2 zK = make_float2(p[8], p[9]);          // z^1024
        float2 V  = make_float2(1.0f, 0.0f);          // -> z^(1024*g)
        for (int k = 0; k < g; ++k) V = cmulf(V, zK);
        unsigned short* arow0 = smem + A_OFF + (g * 16) * KSA;
#pragma unroll
        for (int r = 0; r < 16; ++r) {
            unsigned* wrow = (unsigned*)(arow0 + r * KSA);
            wrow[n] = pack_bf_rn(V.x, -V.y);
            V = cmulf(V, w);
        }
    }

    // ---- build B (P-side): rows i = 8g..8g+7, P = 2Ceff*z^i ----
    {
        float2 z  = make_float2(p[2], p[3]);
        float2 z8 = make_float2(p[4], p[5]);
        float2 u  = make_float2(p[0], p[1]);          // 2*Ceff
        for (int k = 0; k < g; ++k) u = cmulf(u, z8); // -> 2Ceff * z^(8g)
        unsigned short* brow0 = smem + B_OFF + (g * 8) * KSB;
#pragma unroll
        for (int r = 0; r < 8; ++r) {
            unsigned* wrow = (unsigned*)(brow0 + r * KSB);
            wrow[n] = pack_bf_rn(u.x, u.y);
            u = cmulf(u, z);
        }
    }
    __syncthreads();

    // ---- MFMA phase: out2[jj][i], wave w owns jj in [w*32, w*32+32) ----
    const int lane = tid & 63;
    const int w    = tid >> 6;
    const int m    = lane & 15;
    const int q    = lane >> 4;

    const char* sb = (const char*)smem_raw;

    B128 ah[2][2];
#pragma unroll
    for (int jt = 0; jt < 2; ++jt) {
        const int abyte = (A_OFF + (w * 32 + jt * 16 + m) * KSA) * 2;
        ah[jt][0].f4 = *(const float4*)(sb + abyte + q * 16);        // k 0..31
        ah[jt][1].f4 = *(const float4*)(sb + abyte + 64 + q * 16);   // k 32..63
    }

    f32x4 acc[2][4];
#pragma unroll
    for (int jt = 0; jt < 2; ++jt)
#pragma unroll
        for (int it = 0; it < 4; ++it)
            acc[jt][it] = (f32x4){0.f, 0.f, 0.f, 0.f};

#pragma unroll
    for (int it = 0; it < 4; ++it) {
        const int bbyte = (B_OFF + (it * 16 + m) * KSB) * 2;
        B128 b0, b1;
        b0.f4 = *(const float4*)(sb + bbyte + q * 16);          // k 0..31
        b1.f4 = *(const float4*)(sb + bbyte + 64 + q * 16);     // k 32..63
#pragma unroll
        for (int jt = 0; jt < 2; ++jt) {
            f32x4 a = acc[jt][it];
            a = __builtin_amdgcn_mfma_f32_16x16x32_bf16(ah[jt][0].b8, b0.b8, a, 0, 0, 0);
            a = __builtin_amdgcn_mfma_f32_16x16x32_bf16(ah[jt][1].b8, b1.b8, a, 0, 0, 0);
            acc[jt][it] = a;
        }
    }

    // All LDS reads of A/B are complete across the block after this barrier;
    // the staging buffer may now overwrite them.
    __syncthreads();

    // ---- stage transposed output in LDS (swizzled; <=2-way on write) ----
    // D[row][col] -> logical word l = 64*jj + 16*it + m,
    //   jj = w*32 + jt*16 + q*4 + reg, col = it*16 + m
#pragma unroll
    for (int jt = 0; jt < 2; ++jt) {
#pragma unroll
        for (int it = 0; it < 4; ++it) {
#pragma unroll
            for (int reg = 0; reg < 4; ++reg) {
                const int jj = w * 32 + jt * 16 + q * 4 + reg;
                const int l  = (jj << 6) + (it << 4) + m;
                stage[swz(l)] = acc[jt][it][reg];
            }
        }
    }
    __syncthreads();

    // ---- fully-coalesced epilogue: 8x dwordx4, 1 KiB contiguous per wave ----
    float* op = out + (size_t)h * L_LEN;
#pragma unroll
    for (int r = 0; r < 8; ++r) {
        const int widx = (r << 10) + (tid << 2);
        const f32x4 v = *(const f32x4*)(stage + swz(widx));
        __builtin_nontemporal_store(v, (f32x4*)(op + widx));
    }
}

extern "C" void kernel_launch(void* const* d_in, const int* in_sizes, int n_in,
                              void* d_out, int out_size, void* d_ws, size_t ws_size,
                              hipStream_t stream) {
    const float* C          = (const float*)d_in[0];
    const float* log_dt     = (const float*)d_in[1];
    const float* log_A_real = (const float*)d_in[2];
    const float* A_imag     = (const float*)d_in[3];
    float* out              = (float*)d_out;

    dim3 grid(H_DIM);   // one block per h
    dim3 block(TPB);
    hipLaunchKernelGGL(s4d_mfma5_kernel, grid, block, 0, stream,
                       C, log_dt, log_A_real, A_imag, out);
}